// Round 17
// baseline (236.372 us; speedup 1.0000x reference)
//
#include <hip/hip_runtime.h>
#include <cfloat>

#define N_NODES 50000
#define N_EDGES 1600000
#define DX      128
#define DH      64
#define KH      4
#define NC      256                   // KH*DH
#define NEG_SLOPE 0.01f
#define SCAN_BLOCKS 196               // bucket count (dst>>8)
#define BIN_BLOCKS 625
#define BIN_CHUNK  2560               // 625*2560 = 1.6M edges exactly
#define BIN_CAP    10000              // padded bucket capacity (mean 8192, sd ~90)
#define GEMM_BLOCKS 782               // 781*64 + 16 = 50000 nodes, 64/block
#define CS_REP  64                    // colsum replicas (contention ~195/addr)
#define XPK_BLOCKS 3125               // 50000*128/8/256 — x bf16-split pre-pack

typedef float f2 __attribute__((ext_vector_type(2)));
typedef short s8v __attribute__((ext_vector_type(8)));
typedef float f4v __attribute__((ext_vector_type(4)));
typedef unsigned short ushort_t;

__device__ __forceinline__ unsigned pack_bf16(float a, float b) {
    unsigned ua = __float_as_uint(a), ub = __float_as_uint(b);
    ua = (ua + 0x7FFFu + ((ua >> 16) & 1u)) >> 16;          // RNE
    ub = (ub + 0x7FFFu + ((ub >> 16) & 1u)) & 0xFFFF0000u;
    return ua | ub;
}
__device__ __forceinline__ float bflo(unsigned u) { return __uint_as_float(u << 16); }
__device__ __forceinline__ float bfhi(unsigned u) { return __uint_as_float(u & 0xFFFF0000u); }

// ---------- setup: blocks [0,128) seat bcur/colsumR + build B frags;
//            blocks [128,3253) pre-split x into bf16 hi (xh) + residual (xl). ----------
__global__ void k_setup(const float* __restrict__ Ww, const float* __restrict__ x,
                        ushort_t* __restrict__ Bh, ushort_t* __restrict__ Bl,
                        ushort_t* __restrict__ xh, ushort_t* __restrict__ xl,
                        int* __restrict__ bcur, float* __restrict__ colsumR) {
    if (blockIdx.x >= 128) {
        // x pre-pack: 8 floats/thread, coalesced float4 loads, uint4 stores
        int idx = (blockIdx.x - 128) * 256 + threadIdx.x;   // 800000 exactly
        const float4* xp = (const float4*)x + (size_t)idx * 2;
        float4 a = xp[0], b = xp[1];
        uint4 h, l;
        h.x = pack_bf16(a.x, a.y); h.y = pack_bf16(a.z, a.w);
        h.z = pack_bf16(b.x, b.y); h.w = pack_bf16(b.z, b.w);
        l.x = pack_bf16(a.x - bflo(h.x), a.y - bfhi(h.x));
        l.y = pack_bf16(a.z - bflo(h.y), a.w - bfhi(h.y));
        l.z = pack_bf16(b.x - bflo(h.z), b.y - bfhi(h.z));
        l.w = pack_bf16(b.z - bflo(h.w), b.w - bfhi(h.w));
        ((uint4*)xh)[idx] = h;
        ((uint4*)xl)[idx] = l;
        return;
    }
    int i = blockIdx.x * 256 + threadIdx.x;   // 32768 threads, one bf16 each
    if (i < SCAN_BLOCKS) bcur[i] = i * BIN_CAP;
    if (i < CS_REP * NC) colsumR[i] = 0.f;
    int e = i & 7, lane = (i >> 3) & 63, ct = (i >> 9) & 15, kt = (i >> 13) & 3;
    int k = kt * 32 + ((lane >> 4) << 3) + e;
    int c = ct * 16 + (lane & 15);
    float v = Ww[c * DX + k];
    unsigned uv = __float_as_uint(v);
    unsigned vh = (uv + 0x7FFFu + ((uv >> 16) & 1u)) >> 16;
    float rem = v - __uint_as_float(vh << 16);
    unsigned ur = __float_as_uint(rem);
    unsigned vl = (ur + 0x7FFFu + ((ur >> 16) & 1u)) >> 16;
    Bh[i] = (ushort_t)vh;
    Bl[i] = (ushort_t)vl;
}

// ---------- fused: blocks [0,782) = Wx MFMA GEMM (pre-packed A frags, B-regs hoisted);
//            blocks [782,1407) = edge binning. Paths are data-independent. ----------
__global__ void __launch_bounds__(256) k_gemm1bin(const ushort_t* __restrict__ xh,
                                                  const ushort_t* __restrict__ xl,
                                                  const uint4* __restrict__ Bh,
                                                  const uint4* __restrict__ Bl,
                                                  const float* __restrict__ Wb,
                                                  const float* __restrict__ aw,
                                                  const float* __restrict__ ab,
                                                  unsigned* __restrict__ Wx8,
                                                  float* __restrict__ smeta,
                                                  float* __restrict__ sic,
                                                  const int* __restrict__ ei,
                                                  int* __restrict__ bcur,
                                                  unsigned* __restrict__ binned) {
    __shared__ float lds_wx[16][264];
    __shared__ int bh[SCAN_BLOCKS];   // bin path: count, then local cursor
    __shared__ int bb[SCAN_BLOCKS];   // bin path: reserved global base

    if (blockIdx.x >= GEMM_BLOCKS) {
        // ================= bin path =================
        int t = threadIdx.x;
        if (t < SCAN_BLOCKS) bh[t] = 0;
        __syncthreads();
        int e0 = (blockIdx.x - GEMM_BLOCKS) * BIN_CHUNK;
#pragma unroll 5
        for (int k = 0; k < BIN_CHUNK / 256; ++k) {
            int dst = ei[N_EDGES + e0 + t + k * 256];
            atomicAdd(&bh[dst >> 8], 1);
        }
        __syncthreads();
        if (t < SCAN_BLOCKS) {
            bb[t] = atomicAdd(&bcur[t], bh[t]);   // bcur seeded at t*BIN_CAP
            bh[t] = 0;
        }
        __syncthreads();
#pragma unroll 5
        for (int k = 0; k < BIN_CHUNK / 256; ++k) {
            int e = e0 + t + k * 256;
            int src = ei[e];
            int dst = ei[N_EDGES + e];
            int b = dst >> 8;
            int lo = atomicAdd(&bh[b], 1);
            binned[bb[b] + lo] = (unsigned)src | ((unsigned)(dst & 255) << 16);  // src < 2^16
        }
        return;
    }

    // ================= gemm1 path: 64 nodes/block, 4 node-groups of 16 =================
    int n0b = blockIdx.x * 64;
    int wv = __builtin_amdgcn_readfirstlane(threadIdx.x >> 6);
    int lane = threadIdx.x & 63;
    int arow = lane & 15, agrp = lane >> 4;
    f4v acc[4][4];                             // [ct][ng] — fully unrolled indexing only
#pragma unroll
    for (int ct = 0; ct < 4; ++ct)
#pragma unroll
        for (int ng = 0; ng < 4; ++ng) acc[ct][ng] = {0.f, 0.f, 0.f, 0.f};

#pragma unroll
    for (int kt = 0; kt < 4; ++kt) {
        // hoist this kt's B fragments into registers (reused by 4 node-groups)
        s8v bh8[4], bl8[4];
#pragma unroll
        for (int ct = 0; ct < 4; ++ct) {
            int ctg = wv * 4 + ct;             // global col-tile 0..15
            bh8[ct] = __builtin_bit_cast(s8v, Bh[(kt * 16 + ctg) * 64 + lane]);
            bl8[ct] = __builtin_bit_cast(s8v, Bl[(kt * 16 + ctg) * 64 + lane]);
        }
#pragma unroll
        for (int ng = 0; ng < 4; ++ng) {
            int node = n0b + ng * 16 + arow;
            if (node > N_NODES - 1) node = N_NODES - 1;   // tail clamp (loads only)
            size_t off = ((size_t)node * DX + agrp * 8 + kt * 32) >> 3;   // uint4 index
            s8v ah = __builtin_bit_cast(s8v, ((const uint4*)xh)[off]);
            s8v al = __builtin_bit_cast(s8v, ((const uint4*)xl)[off]);
#pragma unroll
            for (int ct = 0; ct < 4; ++ct) {
                acc[ct][ng] = __builtin_amdgcn_mfma_f32_16x16x32_bf16(ah, bh8[ct], acc[ct][ng], 0, 0, 0);
                acc[ct][ng] = __builtin_amdgcn_mfma_f32_16x16x32_bf16(al, bh8[ct], acc[ct][ng], 0, 0, 0);
                acc[ct][ng] = __builtin_amdgcn_mfma_f32_16x16x32_bf16(ah, bl8[ct], acc[ct][ng], 0, 0, 0);
            }
        }
    }

    // epilogue per node-group (reuses the 16-row LDS tile 4x)
    int kh = lane >> 4, lq = lane & 15;
    float4 bias = ((const float4*)Wb)[lane];
    const float* awi = aw + kh * 2 * DH + lq * 4;
    const float* awj = awi + DH;
    float ai0 = awi[0], ai1 = awi[1], ai2 = awi[2], ai3 = awi[3];
    float aj0 = awj[0], aj1 = awj[1], aj2 = awj[2], aj3 = awj[3];
    float abk = ab[kh];
#pragma unroll
    for (int ng = 0; ng < 4; ++ng) {
        __syncthreads();
#pragma unroll
        for (int ct = 0; ct < 4; ++ct) {
            int c = wv * 64 + ct * 16 + arow;
            int r0 = agrp * 4;
            lds_wx[r0 + 0][c] = acc[ct][ng].x;
            lds_wx[r0 + 1][c] = acc[ct][ng].y;
            lds_wx[r0 + 2][c] = acc[ct][ng].z;
            lds_wx[r0 + 3][c] = acc[ct][ng].w;
        }
        __syncthreads();
#pragma unroll
        for (int rr = 0; rr < 4; ++rr) {
            int r = wv * 4 + rr;
            int node = n0b + ng * 16 + r;
            float4 o4 = *(float4*)&lds_wx[r][4 * lane];
            float o0 = o4.x + bias.x, o1 = o4.y + bias.y;
            float o2 = o4.z + bias.z, o3 = o4.w + bias.w;
            float pi = o0 * ai0 + o1 * ai1 + o2 * ai2 + o3 * ai3;
            float pj = o0 * aj0 + o1 * aj1 + o2 * aj2 + o3 * aj3;
            float am = fmaxf(fmaxf(fabsf(o0), fabsf(o1)), fmaxf(fabsf(o2), fabsf(o3)));
#pragma unroll
            for (int off = 8; off >= 1; off >>= 1) {
                pi += __shfl_xor(pi, off, 64);
                pj += __shfl_xor(pj, off, 64);
                am = fmaxf(am, __shfl_xor(am, off, 64));
            }
            am = fmaxf(am, 1e-20f);
            float rs = 127.f / am;
            int q0 = __float2int_rn(o0 * rs) + 128;
            int q1 = __float2int_rn(o1 * rs) + 128;
            int q2 = __float2int_rn(o2 * rs) + 128;
            int q3 = __float2int_rn(o3 * rs) + 128;
            unsigned pk = (unsigned)q0 | ((unsigned)q1 << 8) |
                          ((unsigned)q2 << 16) | ((unsigned)q3 << 24);
            if (node < N_NODES) {
                Wx8[(size_t)node * 64 + lane] = pk;
                if (lq == 0) {
                    sic[(size_t)node * 4 + kh] = pi + abk;     // fold ab into dst-side score
                    smeta[(size_t)node * 8 + kh] = pj;         // src-side score
                    smeta[(size_t)node * 8 + 4 + kh] = am * (1.f / 127.f);  // dequant scale
                }
            }
        }
    }
}

// ---------- per-bucket LDS counting-sort: histogram + scan + sort in LDS + coalesced copy ----------
__global__ void __launch_bounds__(1024) k_scatter3(const unsigned* __restrict__ binned,
                                                   const int* __restrict__ bcur,
                                                   int* __restrict__ rowstart,
                                                   int* __restrict__ rowend,
                                                   int* __restrict__ csr_src) {
    __shared__ int lcnt[256];
    __shared__ int lcur[256];
    __shared__ int s[256];
    __shared__ int srt[BIN_CAP + 256];   // sorted bucket segment (self-loops + edges)
    int t = threadIdx.x, b = blockIdx.x;
    int e0 = b * BIN_CAP, e1 = bcur[b];
    int n = e1 - e0;
    int nself = min(256, N_NODES - b * 256);   // valid dsts in this bucket
    if (t < 256) lcnt[t] = 0;
    __syncthreads();
    for (int i = e0 + t; i < e1; i += 1024)
        atomicAdd(&lcnt[binned[i] >> 16], 1);
    __syncthreads();
    int v = (t < 256) ? lcnt[t] : 0;
    if (t < 256) s[t] = v;
    __syncthreads();
#pragma unroll
    for (int off = 1; off < 256; off <<= 1) {
        int u = (t >= off && t < 256) ? s[t - off] : 0;
        __syncthreads();
        if (t < 256) s[t] += u;
        __syncthreads();
    }
    int base_b = b * (BIN_CAP + 256);   // padded csr base for this bucket
    if (t < 256) {
        int d = b * 256 + t;
        if (d < N_NODES) {
            int ls = (s[t] - v) + t;        // local start (incl. t self-loops before)
            rowstart[d] = base_b + ls;
            rowend[d] = base_b + ls + 1 + v;   // self-loop + v edges
            srt[ls] = d;                       // self-loop edge placed first
            lcur[t] = ls + 1;
        } else lcur[t] = 0;
    }
    __syncthreads();
    for (int i = e0 + t; i < e1; i += 1024) {
        unsigned u = binned[i];
        int pos = atomicAdd(&lcur[u >> 16], 1);
        srt[pos] = (int)(u & 0xFFFFu);       // random write -> LDS (cheap)
    }
    __syncthreads();
    int tot = n + nself;
    for (int i = t; i < tot; i += 1024)
        csr_src[base_b + i] = srt[i];        // coalesced linear copy out
}

// ---------- aggregation + fused colsum (64-way replicated): int8 messages, 8-deep pipeline ----------
__global__ void __launch_bounds__(256) k_aggregate(const int* __restrict__ rowstart,
                                                   const int* __restrict__ rowend,
                                                   const int* __restrict__ csr_src,
                                                   const float* __restrict__ sic,
                                                   const float* __restrict__ smeta,
                                                   const unsigned* __restrict__ Wx8,
                                                   unsigned* __restrict__ expb,
                                                   float* __restrict__ colsumR) {
    __shared__ float exls[4][64 * 4];                 // per-wave: 64 edges x 4 heads
    int wv = threadIdx.x >> 6;
    int dst = blockIdx.x * 4 + wv;                    // grid = 12500, exact
    int lane = threadIdx.x & 63;
    int kh = lane >> 4;
    int i0 = rowstart[dst], i1 = rowend[dst];
    float4 si = *(const float4*)&sic[(size_t)dst * 4];   // broadcast (ab folded)
    float* exl = exls[wv];
    const float* exb = exl + kh;
    const float4* sm4 = (const float4*)smeta;
    const char* wxp = (const char*)Wx8;
    size_t loff = (size_t)lane * 4;

    f2 acc01 = {0.f, 0.f}, acc23 = {0.f, 0.f};
    float den0 = 0.f, den1 = 0.f, den2 = 0.f, den3 = 0.f;
    float ds0 = 0.f, ds1 = 0.f, ds2 = 0.f, ds3 = 0.f;

    for (int b = i0; b < i1; b += 64) {
        int cnt = i1 - b;
        if (cnt > 64) cnt = 64;
        int ngrp = (cnt + 7) >> 3;
        // ---- phase A: one edge per lane ----
        int idx = b + lane;
        if (lane >= cnt) idx = i1 - 1;
        int sl = __builtin_nontemporal_load(&csr_src[idx]);
        float4 mj = sm4[(size_t)sl * 2];
        float4 ms = sm4[(size_t)sl * 2 + 1];
        // pre-issue gather groups 0 and 1 (depend only on sl)
        unsigned gA[8], gB[8];
#pragma unroll
        for (int u = 0; u < 8; ++u) {
            int s = __builtin_amdgcn_readlane(sl, u);
            gA[u] = *(const unsigned*)(wxp + (((size_t)(unsigned)s) << 8) + loff);
        }
        if (ngrp > 1) {
#pragma unroll
            for (int u = 0; u < 8; ++u) {
                int s = __builtin_amdgcn_readlane(sl, 8 + u);
                gB[u] = *(const unsigned*)(wxp + (((size_t)(unsigned)s) << 8) + loff);
            }
        }
        float xs0 = 0.f, xs1 = 0.f, xs2 = 0.f, xs3 = 0.f;
        if (lane < cnt) {
            float e0 = si.x + mj.x, e1 = si.y + mj.y;
            float e2 = si.z + mj.z, e3 = si.w + mj.w;
            e0 = fmaxf(e0, NEG_SLOPE * e0);
            e1 = fmaxf(e1, NEG_SLOPE * e1);
            e2 = fmaxf(e2, NEG_SLOPE * e2);
            e3 = fmaxf(e3, NEG_SLOPE * e3);
            float ex0 = __expf(e0), ex1 = __expf(e1);
            float ex2 = __expf(e2), ex3 = __expf(e3);
            den0 += ex0; den1 += ex1; den2 += ex2; den3 += ex3;
            xs0 = ex0 * ms.x; xs1 = ex1 * ms.y;
            xs2 = ex2 * ms.z; xs3 = ex3 * ms.w;
            ds0 += xs0; ds1 += xs1; ds2 += xs2; ds3 += xs3;
        }
        *(float4*)&exl[lane * 4] = make_float4(xs0, xs1, xs2, xs3);
        asm volatile("" ::: "memory");    // keep phase A stores before phase B reads
        // ---- phase B: consume groups, 2-bank pipeline ----
        for (int g = 0; g < ngrp; g += 2) {
#pragma unroll
            for (int u = 0; u < 8; ++u) {
                float ev = exb[(size_t)(g * 8 + u) * 4];
                f2 w01 = {(float)(gA[u] & 0xFFu), (float)((gA[u] >> 8) & 0xFFu)};
                f2 w23 = {(float)((gA[u] >> 16) & 0xFFu), (float)(gA[u] >> 24)};
                f2 e2 = {ev, ev};
                acc01 = __builtin_elementwise_fma(w01, e2, acc01);
                acc23 = __builtin_elementwise_fma(w23, e2, acc23);
            }
            if (g + 2 < ngrp) {
#pragma unroll
                for (int u = 0; u < 8; ++u) {
                    int s = __builtin_amdgcn_readlane(sl, (g + 2) * 8 + u);
                    gA[u] = *(const unsigned*)(wxp + (((size_t)(unsigned)s) << 8) + loff);
                }
            }
            if (g + 1 < ngrp) {
#pragma unroll
                for (int u = 0; u < 8; ++u) {
                    float ev = exb[(size_t)((g + 1) * 8 + u) * 4];
                    f2 w01 = {(float)(gB[u] & 0xFFu), (float)((gB[u] >> 8) & 0xFFu)};
                    f2 w23 = {(float)((gB[u] >> 16) & 0xFFu), (float)(gB[u] >> 24)};
                    f2 e2 = {ev, ev};
                    acc01 = __builtin_elementwise_fma(w01, e2, acc01);
                    acc23 = __builtin_elementwise_fma(w23, e2, acc23);
                }
                if (g + 3 < ngrp) {
#pragma unroll
                    for (int u = 0; u < 8; ++u) {
                        int s = __builtin_amdgcn_readlane(sl, (g + 3) * 8 + u);
                        gB[u] = *(const unsigned*)(wxp + (((size_t)(unsigned)s) << 8) + loff);
                    }
                }
            }
        }
        asm volatile("" ::: "memory");    // keep next batch's stores after these reads
    }

    // ---- den/dsum reduce: fold 16-lane groups, select my head, butterfly ----
    den0 += __shfl_xor(den0, 16, 64); den0 += __shfl_xor(den0, 32, 64);
    den1 += __shfl_xor(den1, 16, 64); den1 += __shfl_xor(den1, 32, 64);
    den2 += __shfl_xor(den2, 16, 64); den2 += __shfl_xor(den2, 32, 64);
    den3 += __shfl_xor(den3, 16, 64); den3 += __shfl_xor(den3, 32, 64);
    ds0 += __shfl_xor(ds0, 16, 64); ds0 += __shfl_xor(ds0, 32, 64);
    ds1 += __shfl_xor(ds1, 16, 64); ds1 += __shfl_xor(ds1, 32, 64);
    ds2 += __shfl_xor(ds2, 16, 64); ds2 += __shfl_xor(ds2, 32, 64);
    ds3 += __shfl_xor(ds3, 16, 64); ds3 += __shfl_xor(ds3, 32, 64);
    float dsel  = (kh < 2) ? ((kh == 0) ? den0 : den1) : ((kh == 2) ? den2 : den3);
    float dssel = (kh < 2) ? ((kh == 0) ? ds0  : ds1)  : ((kh == 2) ? ds2  : ds3);
#pragma unroll
    for (int off = 1; off <= 8; off <<= 1) {
        dsel  += __shfl_xor(dsel, off, 64);
        dssel += __shfl_xor(dssel, off, 64);
    }

    float r = 1.f / dsel;
    float bias = 128.f * dssel;
    float o0 = __expf((acc01.x - bias) * r), o1 = __expf((acc01.y - bias) * r);
    float o2 = __expf((acc23.x - bias) * r), o3 = __expf((acc23.y - bias) * r);
    unsigned long long pk = (unsigned long long)pack_bf16(o0, o1) |
                            ((unsigned long long)pack_bf16(o2, o3) << 32);
    __builtin_nontemporal_store(pk,
        (unsigned long long*)&expb[(size_t)dst * 128 + lane * 2]);  // bf16, cols 4l..4l+3

    // ---- fused colsum: block reduce in dead exls, 1 atomic/thread to replica bid&63 ----
    *(float4*)&exl[lane * 4] = make_float4(o0, o1, o2, o3);   // exl[col] for cols 4l..4l+3
    __syncthreads();
    int t = threadIdx.x;
    float cs = exls[0][t] + exls[1][t] + exls[2][t] + exls[3][t];
    atomicAdd(&colsumR[((blockIdx.x & (CS_REP - 1)) << 8) + t], cs);
}

// ---------- Ws frags: sum 64 colsum replicas, split(Wo_w^T / colsum), MFMA order ----------
__global__ void k_prepWs(const float* __restrict__ Wo_w, const float* __restrict__ colsumR,
                         ushort_t* __restrict__ Wsh, ushort_t* __restrict__ Wsl) {
    int i = blockIdx.x * 256 + threadIdx.x;   // 16384 total
    int e = i & 7, lane = (i >> 3) & 63, ct = (i >> 9) & 3, kt = (i >> 11) & 7;
    int c = kt * 32 + ((lane >> 4) << 3) + e;
    int j = ct * 16 + (lane & 15);
    float s = 0.f;
#pragma unroll 8
    for (int rp = 0; rp < CS_REP; ++rp) s += colsumR[rp * NC + c];
    float v = Wo_w[j * NC + c] / s;
    unsigned uv = __float_as_uint(v);
    unsigned vh = (uv + 0x7FFFu + ((uv >> 16) & 1u)) >> 16;
    float rem = v - __uint_as_float(vh << 16);
    unsigned ur = __float_as_uint(rem);
    unsigned vl = (ur + 0x7FFFu + ((ur >> 16) & 1u)) >> 16;
    Wsh[i] = (ushort_t)vh;
    Wsl[i] = (ushort_t)vl;
}

// ---------- out = expb @ (Wsh+Wsl) + b via MFMA; A = expb bf16 (exact) ----------
__global__ void __launch_bounds__(256) k_out(const unsigned* __restrict__ expb,
                                             const uint4* __restrict__ Wsh,
                                             const uint4* __restrict__ Wsl,
                                             const float* __restrict__ Wo_b,
                                             float* __restrict__ out) {
    int n0 = blockIdx.x * 16;                  // 3125 exact
    int wv = __builtin_amdgcn_readfirstlane(threadIdx.x >> 6);
    int lane = threadIdx.x & 63;
    int arow = lane & 15, agrp = lane >> 4;
    const unsigned* ar = expb + (size_t)(n0 + arow) * 128 + agrp * 4;
    f4v acc = {0.f, 0.f, 0.f, 0.f};
#pragma unroll
    for (int kt = 0; kt < 8; ++kt) {
        uint4 av = *(const uint4*)(ar + kt * 16);       // 8 bf16: cols kt*32+agrp*8 ..+7
        uint4 bh = Wsh[(kt * 4 + wv) * 64 + lane];
        uint4 bl = Wsl[(kt * 4 + wv) * 64 + lane];
        s8v a8 = __builtin_bit_cast(s8v, av);
        acc = __builtin_amdgcn_mfma_f32_16x16x32_bf16(a8, __builtin_bit_cast(s8v, bh), acc, 0, 0, 0);
        acc = __builtin_amdgcn_mfma_f32_16x16x32_bf16(a8, __builtin_bit_cast(s8v, bl), acc, 0, 0, 0);
    }
    int j = wv * 16 + arow;                    // D: col = lane&15
    float bj = Wo_b[j];
#pragma unroll
    for (int r = 0; r < 4; ++r) {              // D: row = agrp*4 + r
        int node = n0 + agrp * 4 + r;
        out[(size_t)node * DH + j] = acc[r] + bj;
    }
}

extern "C" void kernel_launch(void* const* d_in, const int* in_sizes, int n_in,
                              void* d_out, int out_size, void* d_ws, size_t ws_size,
                              hipStream_t stream) {
    const int*   ei   = (const int*)d_in[0];     // int32 from harness
    const float* x    = (const float*)d_in[1];
    const float* Ww   = (const float*)d_in[2];
    const float* Wb   = (const float*)d_in[3];
    const float* aw   = (const float*)d_in[4];
    const float* ab   = (const float*)d_in[5];
    const float* Wo_w = (const float*)d_in[6];
    const float* Wo_b = (const float*)d_in[7];
    float* out = (float*)d_out;

    char* p = (char*)d_ws;
    auto alloc = [&](size_t bytes) -> char* {
        char* q = p;
        p += (bytes + 255) & ~(size_t)255;
        return q;
    };
    unsigned* Wx8      = (unsigned*)alloc((size_t)N_NODES * NC);    // int8 Wx copy (12.8MB)
    unsigned* expb     = (unsigned*)alloc((size_t)N_NODES * NC * 2);// bf16 exp(agg)
    ushort_t* Bh       = (ushort_t*)alloc((size_t)DX * NC * 2);     // bf16 W frags (hi)
    ushort_t* Bl       = (ushort_t*)alloc((size_t)DX * NC * 2);     // bf16 W frags (residual)
    ushort_t* xh       = (ushort_t*)alloc((size_t)N_NODES * DX * 2);// bf16 x (hi)
    ushort_t* xl       = (ushort_t*)alloc((size_t)N_NODES * DX * 2);// bf16 x (residual)
    ushort_t* Wsh      = (ushort_t*)alloc((size_t)NC * DH * 2);     // bf16 Ws frags (hi)
    ushort_t* Wsl      = (ushort_t*)alloc((size_t)NC * DH * 2);     // bf16 Ws frags (residual)
    float*    smeta    = (float*)alloc((size_t)N_NODES * 8 * 4);    // {sj[4], scale[4]} per node
    float*    sic      = (float*)alloc((size_t)N_NODES * 4 * 4);
    int*      rowstart = (int*)alloc((size_t)N_NODES * 4);
    int*      rowend   = (int*)alloc((size_t)N_NODES * 4);
    int*      csr_src  = (int*)alloc((size_t)SCAN_BLOCKS * (BIN_CAP + 256) * 4);  // padded CSR
    unsigned* binned   = (unsigned*)alloc((size_t)SCAN_BLOCKS * BIN_CAP * 4);     // padded buckets
    float*    colsumR  = (float*)alloc((size_t)CS_REP * NC * 4);    // 64 replicas
    int*      bcur     = (int*)alloc(SCAN_BLOCKS * 4);

    k_setup<<<128 + XPK_BLOCKS, 256, 0, stream>>>(Ww, x, Bh, Bl, xh, xl, bcur, colsumR);
    k_gemm1bin<<<GEMM_BLOCKS + BIN_BLOCKS, 256, 0, stream>>>(
        xh, xl, (const uint4*)Bh, (const uint4*)Bl, Wb, aw, ab, Wx8, smeta, sic,
        ei, bcur, binned);
    k_scatter3<<<SCAN_BLOCKS, 1024, 0, stream>>>(binned, bcur, rowstart, rowend, csr_src);
    k_aggregate<<<N_NODES / 4, 256, 0, stream>>>(rowstart, rowend, csr_src, sic, smeta,
                                                 Wx8, expb, colsumR);
    k_prepWs<<<(NC * DH) / 256, 256, 0, stream>>>(Wo_w, colsumR, Wsh, Wsl);
    k_out<<<N_NODES / 16, 256, 0, stream>>>(expb, (const uint4*)Wsh, (const uint4*)Wsl,
                                            Wo_b, out);
}

// Round 18
// 228.747 us; speedup vs baseline: 1.0333x; 1.0333x over previous
//
#include <hip/hip_runtime.h>
#include <cfloat>

#define N_NODES 50000
#define N_EDGES 1600000
#define DX      128
#define DH      64
#define KH      4
#define NC      256                   // KH*DH
#define NEG_SLOPE 0.01f
#define SCAN_BLOCKS 196               // bucket count (dst>>8)
#define BIN_BLOCKS 625
#define BIN_CHUNK  2560               // 625*2560 = 1.6M edges exactly
#define BIN_CAP    10000              // padded bucket capacity (mean 8192, sd ~90)
#define GEMM_BLOCKS 782               // 781*64 + 16 = 50000 nodes, 64/block
#define CS_REP  64                    // colsum replicas (contention ~195/addr)

typedef float f2 __attribute__((ext_vector_type(2)));
typedef short s8v __attribute__((ext_vector_type(8)));
typedef float f4v __attribute__((ext_vector_type(4)));
typedef unsigned short ushort_t;

__device__ __forceinline__ unsigned pack_bf16(float a, float b) {
    unsigned ua = __float_as_uint(a), ub = __float_as_uint(b);
    ua = (ua + 0x7FFFu + ((ua >> 16) & 1u)) >> 16;          // RNE
    ub = (ub + 0x7FFFu + ((ub >> 16) & 1u)) & 0xFFFF0000u;
    return ua | ub;
}
__device__ __forceinline__ float bflo(unsigned u) { return __uint_as_float(u << 16); }
__device__ __forceinline__ float bfhi(unsigned u) { return __uint_as_float(u & 0xFFFF0000u); }

// ---------- setup: seat bcur; zero colsum replicas; build MFMA-lane-ordered B frags ----------
__global__ void k_setup(const float* __restrict__ Ww, ushort_t* __restrict__ Bh,
                        ushort_t* __restrict__ Bl,
                        int* __restrict__ bcur, float* __restrict__ colsumR) {
    int i = blockIdx.x * 256 + threadIdx.x;   // grid 128 -> 32768 threads, one bf16 each
    if (i < SCAN_BLOCKS) bcur[i] = i * BIN_CAP;
    if (i < CS_REP * NC) colsumR[i] = 0.f;
    int e = i & 7, lane = (i >> 3) & 63, ct = (i >> 9) & 15, kt = (i >> 13) & 3;
    int k = kt * 32 + ((lane >> 4) << 3) + e;
    int c = ct * 16 + (lane & 15);
    float v = Ww[c * DX + k];
    unsigned uv = __float_as_uint(v);
    unsigned vh = (uv + 0x7FFFu + ((uv >> 16) & 1u)) >> 16;
    float rem = v - __uint_as_float(vh << 16);
    unsigned ur = __float_as_uint(rem);
    unsigned vl = (ur + 0x7FFFu + ((ur >> 16) & 1u)) >> 16;
    Bh[i] = (ushort_t)vh;
    Bl[i] = (ushort_t)vl;
}

// ---------- fused: blocks [0,782) = Wx MFMA GEMM (64 nodes/block, B-regs hoisted);
//            blocks [782,1407) = edge binning. Paths are data-independent. ----------
__global__ void __launch_bounds__(256) k_gemm1bin(const float* __restrict__ x,
                                                  const uint4* __restrict__ Bh,
                                                  const uint4* __restrict__ Bl,
                                                  const float* __restrict__ Wb,
                                                  const float* __restrict__ aw,
                                                  const float* __restrict__ ab,
                                                  unsigned* __restrict__ Wx8,
                                                  float* __restrict__ smeta,
                                                  float* __restrict__ sic,
                                                  const int* __restrict__ ei,
                                                  int* __restrict__ bcur,
                                                  unsigned* __restrict__ binned) {
    __shared__ float lds_wx[16][264];
    __shared__ int bh[SCAN_BLOCKS];   // bin path: count, then local cursor
    __shared__ int bb[SCAN_BLOCKS];   // bin path: reserved global base

    if (blockIdx.x >= GEMM_BLOCKS) {
        // ================= bin path =================
        int t = threadIdx.x;
        if (t < SCAN_BLOCKS) bh[t] = 0;
        __syncthreads();
        int e0 = (blockIdx.x - GEMM_BLOCKS) * BIN_CHUNK;
#pragma unroll 5
        for (int k = 0; k < BIN_CHUNK / 256; ++k) {
            int dst = ei[N_EDGES + e0 + t + k * 256];
            atomicAdd(&bh[dst >> 8], 1);
        }
        __syncthreads();
        if (t < SCAN_BLOCKS) {
            bb[t] = atomicAdd(&bcur[t], bh[t]);   // bcur seeded at t*BIN_CAP
            bh[t] = 0;
        }
        __syncthreads();
#pragma unroll 5
        for (int k = 0; k < BIN_CHUNK / 256; ++k) {
            int e = e0 + t + k * 256;
            int src = ei[e];
            int dst = ei[N_EDGES + e];
            int b = dst >> 8;
            int lo = atomicAdd(&bh[b], 1);
            binned[bb[b] + lo] = (unsigned)src | ((unsigned)(dst & 255) << 16);  // src < 2^16
        }
        return;
    }

    // ================= gemm1 path: 64 nodes/block, 4 node-groups of 16 =================
    int n0b = blockIdx.x * 64;
    int wv = __builtin_amdgcn_readfirstlane(threadIdx.x >> 6);
    int lane = threadIdx.x & 63;
    int arow = lane & 15, agrp = lane >> 4;
    f4v acc[4][4];                             // [ct][ng] — fully unrolled indexing only
#pragma unroll
    for (int ct = 0; ct < 4; ++ct)
#pragma unroll
        for (int ng = 0; ng < 4; ++ng) acc[ct][ng] = {0.f, 0.f, 0.f, 0.f};

#pragma unroll
    for (int kt = 0; kt < 4; ++kt) {
        // hoist this kt's B fragments into registers (reused by 4 node-groups)
        s8v bh8[4], bl8[4];
#pragma unroll
        for (int ct = 0; ct < 4; ++ct) {
            int ctg = wv * 4 + ct;             // global col-tile 0..15
            bh8[ct] = __builtin_bit_cast(s8v, Bh[(kt * 16 + ctg) * 64 + lane]);
            bl8[ct] = __builtin_bit_cast(s8v, Bl[(kt * 16 + ctg) * 64 + lane]);
        }
#pragma unroll
        for (int ng = 0; ng < 4; ++ng) {
            int node = n0b + ng * 16 + arow;
            if (node > N_NODES - 1) node = N_NODES - 1;   // tail clamp (loads only)
            const float* xr = x + (size_t)node * DX + agrp * 8 + kt * 32;
            float4 xa = *(const float4*)xr;
            float4 xb = *(const float4*)(xr + 4);
            uint4 h, l;
            h.x = pack_bf16(xa.x, xa.y); h.y = pack_bf16(xa.z, xa.w);
            h.z = pack_bf16(xb.x, xb.y); h.w = pack_bf16(xb.z, xb.w);
            l.x = pack_bf16(xa.x - bflo(h.x), xa.y - bfhi(h.x));
            l.y = pack_bf16(xa.z - bflo(h.y), xa.w - bfhi(h.y));
            l.z = pack_bf16(xb.x - bflo(h.z), xb.y - bfhi(h.z));
            l.w = pack_bf16(xb.z - bflo(h.w), xb.w - bfhi(h.w));
            s8v ah = __builtin_bit_cast(s8v, h);
            s8v al = __builtin_bit_cast(s8v, l);
#pragma unroll
            for (int ct = 0; ct < 4; ++ct) {
                acc[ct][ng] = __builtin_amdgcn_mfma_f32_16x16x32_bf16(ah, bh8[ct], acc[ct][ng], 0, 0, 0);
                acc[ct][ng] = __builtin_amdgcn_mfma_f32_16x16x32_bf16(al, bh8[ct], acc[ct][ng], 0, 0, 0);
                acc[ct][ng] = __builtin_amdgcn_mfma_f32_16x16x32_bf16(ah, bl8[ct], acc[ct][ng], 0, 0, 0);
            }
        }
    }

    // epilogue per node-group (reuses the 16-row LDS tile 4x)
    int kh = lane >> 4, lq = lane & 15;
    float4 bias = ((const float4*)Wb)[lane];
    const float* awi = aw + kh * 2 * DH + lq * 4;
    const float* awj = awi + DH;
    float ai0 = awi[0], ai1 = awi[1], ai2 = awi[2], ai3 = awi[3];
    float aj0 = awj[0], aj1 = awj[1], aj2 = awj[2], aj3 = awj[3];
    float abk = ab[kh];
#pragma unroll
    for (int ng = 0; ng < 4; ++ng) {
        __syncthreads();
#pragma unroll
        for (int ct = 0; ct < 4; ++ct) {
            int c = wv * 64 + ct * 16 + arow;
            int r0 = agrp * 4;
            lds_wx[r0 + 0][c] = acc[ct][ng].x;
            lds_wx[r0 + 1][c] = acc[ct][ng].y;
            lds_wx[r0 + 2][c] = acc[ct][ng].z;
            lds_wx[r0 + 3][c] = acc[ct][ng].w;
        }
        __syncthreads();
#pragma unroll
        for (int rr = 0; rr < 4; ++rr) {
            int r = wv * 4 + rr;
            int node = n0b + ng * 16 + r;
            float4 o4 = *(float4*)&lds_wx[r][4 * lane];
            float o0 = o4.x + bias.x, o1 = o4.y + bias.y;
            float o2 = o4.z + bias.z, o3 = o4.w + bias.w;
            float pi = o0 * ai0 + o1 * ai1 + o2 * ai2 + o3 * ai3;
            float pj = o0 * aj0 + o1 * aj1 + o2 * aj2 + o3 * aj3;
            float am = fmaxf(fmaxf(fabsf(o0), fabsf(o1)), fmaxf(fabsf(o2), fabsf(o3)));
#pragma unroll
            for (int off = 8; off >= 1; off >>= 1) {
                pi += __shfl_xor(pi, off, 64);
                pj += __shfl_xor(pj, off, 64);
                am = fmaxf(am, __shfl_xor(am, off, 64));
            }
            am = fmaxf(am, 1e-20f);
            float rs = 127.f / am;
            int q0 = __float2int_rn(o0 * rs) + 128;
            int q1 = __float2int_rn(o1 * rs) + 128;
            int q2 = __float2int_rn(o2 * rs) + 128;
            int q3 = __float2int_rn(o3 * rs) + 128;
            unsigned pk = (unsigned)q0 | ((unsigned)q1 << 8) |
                          ((unsigned)q2 << 16) | ((unsigned)q3 << 24);
            if (node < N_NODES) {
                Wx8[(size_t)node * 64 + lane] = pk;
                if (lq == 0) {
                    sic[(size_t)node * 4 + kh] = pi + abk;     // fold ab into dst-side score
                    smeta[(size_t)node * 8 + kh] = pj;         // src-side score
                    smeta[(size_t)node * 8 + 4 + kh] = am * (1.f / 127.f);  // dequant scale
                }
            }
        }
    }
}

// ---------- per-bucket LDS counting-sort: histogram + scan + sort in LDS + coalesced copy ----------
__global__ void __launch_bounds__(1024) k_scatter3(const unsigned* __restrict__ binned,
                                                   const int* __restrict__ bcur,
                                                   int* __restrict__ rowstart,
                                                   int* __restrict__ rowend,
                                                   int* __restrict__ csr_src) {
    __shared__ int lcnt[256];
    __shared__ int lcur[256];
    __shared__ int s[256];
    __shared__ int srt[BIN_CAP + 256];   // sorted bucket segment (self-loops + edges)
    int t = threadIdx.x, b = blockIdx.x;
    int e0 = b * BIN_CAP, e1 = bcur[b];
    int n = e1 - e0;
    int nself = min(256, N_NODES - b * 256);   // valid dsts in this bucket
    if (t < 256) lcnt[t] = 0;
    __syncthreads();
    for (int i = e0 + t; i < e1; i += 1024)
        atomicAdd(&lcnt[binned[i] >> 16], 1);
    __syncthreads();
    int v = (t < 256) ? lcnt[t] : 0;
    if (t < 256) s[t] = v;
    __syncthreads();
#pragma unroll
    for (int off = 1; off < 256; off <<= 1) {
        int u = (t >= off && t < 256) ? s[t - off] : 0;
        __syncthreads();
        if (t < 256) s[t] += u;
        __syncthreads();
    }
    int base_b = b * (BIN_CAP + 256);   // padded csr base for this bucket
    if (t < 256) {
        int d = b * 256 + t;
        if (d < N_NODES) {
            int ls = (s[t] - v) + t;        // local start (incl. t self-loops before)
            rowstart[d] = base_b + ls;
            rowend[d] = base_b + ls + 1 + v;   // self-loop + v edges
            srt[ls] = d;                       // self-loop edge placed first
            lcur[t] = ls + 1;
        } else lcur[t] = 0;
    }
    __syncthreads();
    for (int i = e0 + t; i < e1; i += 1024) {
        unsigned u = binned[i];
        int pos = atomicAdd(&lcur[u >> 16], 1);
        srt[pos] = (int)(u & 0xFFFFu);       // random write -> LDS (cheap)
    }
    __syncthreads();
    int tot = n + nself;
    for (int i = t; i < tot; i += 1024)
        csr_src[base_b + i] = srt[i];        // coalesced linear copy out
}

// ---------- aggregation + fused colsum (64-way replicated): int8 messages, 8-deep pipeline ----------
__global__ void __launch_bounds__(256) k_aggregate(const int* __restrict__ rowstart,
                                                   const int* __restrict__ rowend,
                                                   const int* __restrict__ csr_src,
                                                   const float* __restrict__ sic,
                                                   const float* __restrict__ smeta,
                                                   const unsigned* __restrict__ Wx8,
                                                   unsigned* __restrict__ expb,
                                                   float* __restrict__ colsumR) {
    __shared__ float exls[4][64 * 4];                 // per-wave: 64 edges x 4 heads
    int wv = threadIdx.x >> 6;
    int dst = blockIdx.x * 4 + wv;                    // grid = 12500, exact
    int lane = threadIdx.x & 63;
    int kh = lane >> 4;
    int i0 = rowstart[dst], i1 = rowend[dst];
    float4 si = *(const float4*)&sic[(size_t)dst * 4];   // broadcast (ab folded)
    float* exl = exls[wv];
    const float* exb = exl + kh;
    const float4* sm4 = (const float4*)smeta;
    const char* wxp = (const char*)Wx8;
    size_t loff = (size_t)lane * 4;

    f2 acc01 = {0.f, 0.f}, acc23 = {0.f, 0.f};
    float den0 = 0.f, den1 = 0.f, den2 = 0.f, den3 = 0.f;
    float ds0 = 0.f, ds1 = 0.f, ds2 = 0.f, ds3 = 0.f;

    for (int b = i0; b < i1; b += 64) {
        int cnt = i1 - b;
        if (cnt > 64) cnt = 64;
        int ngrp = (cnt + 7) >> 3;
        // ---- phase A: one edge per lane ----
        int idx = b + lane;
        if (lane >= cnt) idx = i1 - 1;
        int sl = __builtin_nontemporal_load(&csr_src[idx]);
        float4 mj = sm4[(size_t)sl * 2];
        float4 ms = sm4[(size_t)sl * 2 + 1];
        // pre-issue gather groups 0 and 1 (depend only on sl)
        unsigned gA[8], gB[8];
#pragma unroll
        for (int u = 0; u < 8; ++u) {
            int s = __builtin_amdgcn_readlane(sl, u);
            gA[u] = *(const unsigned*)(wxp + (((size_t)(unsigned)s) << 8) + loff);
        }
        if (ngrp > 1) {
#pragma unroll
            for (int u = 0; u < 8; ++u) {
                int s = __builtin_amdgcn_readlane(sl, 8 + u);
                gB[u] = *(const unsigned*)(wxp + (((size_t)(unsigned)s) << 8) + loff);
            }
        }
        float xs0 = 0.f, xs1 = 0.f, xs2 = 0.f, xs3 = 0.f;
        if (lane < cnt) {
            float e0 = si.x + mj.x, e1 = si.y + mj.y;
            float e2 = si.z + mj.z, e3 = si.w + mj.w;
            e0 = fmaxf(e0, NEG_SLOPE * e0);
            e1 = fmaxf(e1, NEG_SLOPE * e1);
            e2 = fmaxf(e2, NEG_SLOPE * e2);
            e3 = fmaxf(e3, NEG_SLOPE * e3);
            float ex0 = __expf(e0), ex1 = __expf(e1);
            float ex2 = __expf(e2), ex3 = __expf(e3);
            den0 += ex0; den1 += ex1; den2 += ex2; den3 += ex3;
            xs0 = ex0 * ms.x; xs1 = ex1 * ms.y;
            xs2 = ex2 * ms.z; xs3 = ex3 * ms.w;
            ds0 += xs0; ds1 += xs1; ds2 += xs2; ds3 += xs3;
        }
        *(float4*)&exl[lane * 4] = make_float4(xs0, xs1, xs2, xs3);
        asm volatile("" ::: "memory");    // keep phase A stores before phase B reads
        // ---- phase B: consume groups, 2-bank pipeline ----
        for (int g = 0; g < ngrp; g += 2) {
#pragma unroll
            for (int u = 0; u < 8; ++u) {
                float ev = exb[(size_t)(g * 8 + u) * 4];
                f2 w01 = {(float)(gA[u] & 0xFFu), (float)((gA[u] >> 8) & 0xFFu)};
                f2 w23 = {(float)((gA[u] >> 16) & 0xFFu), (float)(gA[u] >> 24)};
                f2 e2 = {ev, ev};
                acc01 = __builtin_elementwise_fma(w01, e2, acc01);
                acc23 = __builtin_elementwise_fma(w23, e2, acc23);
            }
            if (g + 2 < ngrp) {
#pragma unroll
                for (int u = 0; u < 8; ++u) {
                    int s = __builtin_amdgcn_readlane(sl, (g + 2) * 8 + u);
                    gA[u] = *(const unsigned*)(wxp + (((size_t)(unsigned)s) << 8) + loff);
                }
            }
            if (g + 1 < ngrp) {
#pragma unroll
                for (int u = 0; u < 8; ++u) {
                    float ev = exb[(size_t)((g + 1) * 8 + u) * 4];
                    f2 w01 = {(float)(gB[u] & 0xFFu), (float)((gB[u] >> 8) & 0xFFu)};
                    f2 w23 = {(float)((gB[u] >> 16) & 0xFFu), (float)(gB[u] >> 24)};
                    f2 e2 = {ev, ev};
                    acc01 = __builtin_elementwise_fma(w01, e2, acc01);
                    acc23 = __builtin_elementwise_fma(w23, e2, acc23);
                }
                if (g + 3 < ngrp) {
#pragma unroll
                    for (int u = 0; u < 8; ++u) {
                        int s = __builtin_amdgcn_readlane(sl, (g + 3) * 8 + u);
                        gB[u] = *(const unsigned*)(wxp + (((size_t)(unsigned)s) << 8) + loff);
                    }
                }
            }
        }
        asm volatile("" ::: "memory");    // keep next batch's stores after these reads
    }

    // ---- den/dsum reduce: fold 16-lane groups, select my head, butterfly ----
    den0 += __shfl_xor(den0, 16, 64); den0 += __shfl_xor(den0, 32, 64);
    den1 += __shfl_xor(den1, 16, 64); den1 += __shfl_xor(den1, 32, 64);
    den2 += __shfl_xor(den2, 16, 64); den2 += __shfl_xor(den2, 32, 64);
    den3 += __shfl_xor(den3, 16, 64); den3 += __shfl_xor(den3, 32, 64);
    ds0 += __shfl_xor(ds0, 16, 64); ds0 += __shfl_xor(ds0, 32, 64);
    ds1 += __shfl_xor(ds1, 16, 64); ds1 += __shfl_xor(ds1, 32, 64);
    ds2 += __shfl_xor(ds2, 16, 64); ds2 += __shfl_xor(ds2, 32, 64);
    ds3 += __shfl_xor(ds3, 16, 64); ds3 += __shfl_xor(ds3, 32, 64);
    float dsel  = (kh < 2) ? ((kh == 0) ? den0 : den1) : ((kh == 2) ? den2 : den3);
    float dssel = (kh < 2) ? ((kh == 0) ? ds0  : ds1)  : ((kh == 2) ? ds2  : ds3);
#pragma unroll
    for (int off = 1; off <= 8; off <<= 1) {
        dsel  += __shfl_xor(dsel, off, 64);
        dssel += __shfl_xor(dssel, off, 64);
    }

    float r = 1.f / dsel;
    float bias = 128.f * dssel;
    float o0 = __expf((acc01.x - bias) * r), o1 = __expf((acc01.y - bias) * r);
    float o2 = __expf((acc23.x - bias) * r), o3 = __expf((acc23.y - bias) * r);
    unsigned long long pk = (unsigned long long)pack_bf16(o0, o1) |
                            ((unsigned long long)pack_bf16(o2, o3) << 32);
    __builtin_nontemporal_store(pk,
        (unsigned long long*)&expb[(size_t)dst * 128 + lane * 2]);  // bf16, cols 4l..4l+3

    // ---- fused colsum: block reduce in dead exls, 1 atomic/thread to replica bid&63 ----
    *(float4*)&exl[lane * 4] = make_float4(o0, o1, o2, o3);   // exl[col] for cols 4l..4l+3
    __syncthreads();
    int t = threadIdx.x;
    float cs = exls[0][t] + exls[1][t] + exls[2][t] + exls[3][t];
    atomicAdd(&colsumR[((blockIdx.x & (CS_REP - 1)) << 8) + t], cs);
}

// ---------- Ws frags: sum 64 colsum replicas, split(Wo_w^T / colsum), MFMA order ----------
__global__ void k_prepWs(const float* __restrict__ Wo_w, const float* __restrict__ colsumR,
                         ushort_t* __restrict__ Wsh, ushort_t* __restrict__ Wsl) {
    int i = blockIdx.x * 256 + threadIdx.x;   // 16384 total
    int e = i & 7, lane = (i >> 3) & 63, ct = (i >> 9) & 3, kt = (i >> 11) & 7;
    int c = kt * 32 + ((lane >> 4) << 3) + e;
    int j = ct * 16 + (lane & 15);
    float s = 0.f;
#pragma unroll 8
    for (int rp = 0; rp < CS_REP; ++rp) s += colsumR[rp * NC + c];
    float v = Wo_w[j * NC + c] / s;
    unsigned uv = __float_as_uint(v);
    unsigned vh = (uv + 0x7FFFu + ((uv >> 16) & 1u)) >> 16;
    float rem = v - __uint_as_float(vh << 16);
    unsigned ur = __float_as_uint(rem);
    unsigned vl = (ur + 0x7FFFu + ((ur >> 16) & 1u)) >> 16;
    Wsh[i] = (ushort_t)vh;
    Wsl[i] = (ushort_t)vl;
}

// ---------- out = expb @ (Wsh+Wsl) + b via MFMA; 64 nodes/block, B-regs hoisted ----------
// Ws frag traffic drops 100MB -> 25MB (same fix as gemm1's R13 B-hoist).
// Accumulation order per node identical to the 16-node version (bitwise-same out).
__global__ void __launch_bounds__(256) k_out(const unsigned* __restrict__ expb,
                                             const uint4* __restrict__ Wsh,
                                             const uint4* __restrict__ Wsl,
                                             const float* __restrict__ Wo_b,
                                             float* __restrict__ out) {
    int n0b = blockIdx.x * 64;                 // 782 blocks; tail block has 16 valid
    int wv = __builtin_amdgcn_readfirstlane(threadIdx.x >> 6);
    int lane = threadIdx.x & 63;
    int arow = lane & 15, agrp = lane >> 4;
    f4v acc[4];                                // [ng] — fully unrolled indexing only
#pragma unroll
    for (int ng = 0; ng < 4; ++ng) acc[ng] = {0.f, 0.f, 0.f, 0.f};
#pragma unroll
    for (int kt = 0; kt < 8; ++kt) {
        uint4 bh = Wsh[(kt * 4 + wv) * 64 + lane];
        uint4 bl = Wsl[(kt * 4 + wv) * 64 + lane];
        s8v bh8 = __builtin_bit_cast(s8v, bh);
        s8v bl8 = __builtin_bit_cast(s8v, bl);
#pragma unroll
        for (int ng = 0; ng < 4; ++ng) {
            int node = n0b + ng * 16 + arow;
            if (node > N_NODES - 1) node = N_NODES - 1;   // tail clamp (loads only)
            uint4 av = *(const uint4*)(expb + (size_t)node * 128 + agrp * 4 + kt * 16);
            s8v a8 = __builtin_bit_cast(s8v, av);
            acc[ng] = __builtin_amdgcn_mfma_f32_16x16x32_bf16(a8, bh8, acc[ng], 0, 0, 0);
            acc[ng] = __builtin_amdgcn_mfma_f32_16x16x32_bf16(a8, bl8, acc[ng], 0, 0, 0);
        }
    }
    int j = wv * 16 + arow;                    // D: col = lane&15
    float bj = Wo_b[j];
#pragma unroll
    for (int ng = 0; ng < 4; ++ng) {
#pragma unroll
        for (int r = 0; r < 4; ++r) {          // D: row = agrp*4 + r
            int node = n0b + ng * 16 + agrp * 4 + r;
            if (node < N_NODES)
                out[(size_t)node * DH + j] = acc[ng][r] + bj;
        }
    }
}

extern "C" void kernel_launch(void* const* d_in, const int* in_sizes, int n_in,
                              void* d_out, int out_size, void* d_ws, size_t ws_size,
                              hipStream_t stream) {
    const int*   ei   = (const int*)d_in[0];     // int32 from harness
    const float* x    = (const float*)d_in[1];
    const float* Ww   = (const float*)d_in[2];
    const float* Wb   = (const float*)d_in[3];
    const float* aw   = (const float*)d_in[4];
    const float* ab   = (const float*)d_in[5];
    const float* Wo_w = (const float*)d_in[6];
    const float* Wo_b = (const float*)d_in[7];
    float* out = (float*)d_out;

    char* p = (char*)d_ws;
    auto alloc = [&](size_t bytes) -> char* {
        char* q = p;
        p += (bytes + 255) & ~(size_t)255;
        return q;
    };
    unsigned* Wx8      = (unsigned*)alloc((size_t)N_NODES * NC);    // int8 Wx copy (12.8MB)
    unsigned* expb     = (unsigned*)alloc((size_t)N_NODES * NC * 2);// bf16 exp(agg)
    ushort_t* Bh       = (ushort_t*)alloc((size_t)DX * NC * 2);     // bf16 W frags (hi)
    ushort_t* Bl       = (ushort_t*)alloc((size_t)DX * NC * 2);     // bf16 W frags (residual)
    ushort_t* Wsh      = (ushort_t*)alloc((size_t)NC * DH * 2);     // bf16 Ws frags (hi)
    ushort_t* Wsl      = (ushort_t*)alloc((size_t)NC * DH * 2);     // bf16 Ws frags (residual)
    float*    smeta    = (float*)alloc((size_t)N_NODES * 8 * 4);    // {sj[4], scale[4]} per node
    float*    sic      = (float*)alloc((size_t)N_NODES * 4 * 4);
    int*      rowstart = (int*)alloc((size_t)N_NODES * 4);
    int*      rowend   = (int*)alloc((size_t)N_NODES * 4);
    int*      csr_src  = (int*)alloc((size_t)SCAN_BLOCKS * (BIN_CAP + 256) * 4);  // padded CSR
    unsigned* binned   = (unsigned*)alloc((size_t)SCAN_BLOCKS * BIN_CAP * 4);     // padded buckets
    float*    colsumR  = (float*)alloc((size_t)CS_REP * NC * 4);    // 64 replicas
    int*      bcur     = (int*)alloc(SCAN_BLOCKS * 4);

    k_setup<<<128, 256, 0, stream>>>(Ww, Bh, Bl, bcur, colsumR);
    k_gemm1bin<<<GEMM_BLOCKS + BIN_BLOCKS, 256, 0, stream>>>(
        x, (const uint4*)Bh, (const uint4*)Bl, Wb, aw, ab, Wx8, smeta, sic,
        ei, bcur, binned);
    k_scatter3<<<SCAN_BLOCKS, 1024, 0, stream>>>(binned, bcur, rowstart, rowend, csr_src);
    k_aggregate<<<N_NODES / 4, 256, 0, stream>>>(rowstart, rowend, csr_src, sic, smeta,
                                                 Wx8, expb, colsumR);
    k_prepWs<<<(NC * DH) / 256, 256, 0, stream>>>(Wo_w, colsumR, Wsh, Wsl);
    k_out<<<(N_NODES + 63) / 64, 256, 0, stream>>>(expb, (const uint4*)Wsh, (const uint4*)Wsl,
                                                   Wo_b, out);
}